// Round 2
// baseline (1143.612 us; speedup 1.0000x reference)
//
#include <hip/hip_runtime.h>

// Binary-weight MLP: h1=relu(x@sign(w1)^T*s1+b1); h2=relu(h1@...); out=sigmoid(h2@...)
// Strategy: weights -> exact bf16 {-1,0,+1}; activations -> bf16; fp32 MFMA accum;
// scalar scale (mean|w|, computed on device in fp32) applied in fp32 epilogue.
//
// ws layout (160 MB + 256 B), time-multiplexed:
//   scales: 3 floats at ws+0
//   bufA (64 MB): x_bf16, then h2 (x dead after GEMM1)
//   bufB (64 MB): h1
//   bufC (32 MB): sign(w1) -> sign(w2) -> sign(w3)  (each dead after its GEMM)

typedef __bf16 bf16x8 __attribute__((ext_vector_type(8)));
typedef float  f32x4  __attribute__((ext_vector_type(4)));
typedef unsigned short ushort_t;

#define AS1 __attribute__((address_space(1)))
#define AS3 __attribute__((address_space(3)))

__device__ __forceinline__ void async16(const void* g, AS3 void* l) {
    __builtin_amdgcn_global_load_lds((AS1 void*)const_cast<void*>(g), l, 16, 0, 0);
}

__device__ __forceinline__ ushort_t f2bf(float f) {
    unsigned u = __float_as_uint(f);
    u += 0x7FFFu + ((u >> 16) & 1u);   // round-to-nearest-even
    return (ushort_t)(u >> 16);
}

// ---------------- zero the 3 scale accumulators (graph-capture-safe init)
__global__ void zero3_kernel(float* p) {
    if (threadIdx.x < 3) p[threadIdx.x] = 0.f;
}

// ---------------- mean(|w|): grid-stride float4, wave shuffle reduce, 1 atomic/block
__global__ __launch_bounds__(256) void absmean_kernel(const float4* __restrict__ w,
                                                      int n4, float* __restrict__ out) {
    float s = 0.f;
    for (int i = blockIdx.x * blockDim.x + threadIdx.x; i < n4; i += gridDim.x * blockDim.x) {
        float4 v = w[i];
        s += fabsf(v.x) + fabsf(v.y) + fabsf(v.z) + fabsf(v.w);
    }
#pragma unroll
    for (int off = 32; off > 0; off >>= 1) s += __shfl_down(s, off);
    __shared__ float wsum[4];
    if ((threadIdx.x & 63) == 0) wsum[threadIdx.x >> 6] = s;
    __syncthreads();
    if (threadIdx.x == 0) atomicAdd(out, wsum[0] + wsum[1] + wsum[2] + wsum[3]);
}

// ---------------- sign(w) -> bf16 {-1,0,+1} (exact)
__global__ __launch_bounds__(256) void sign_kernel(const float4* __restrict__ w,
                                                   ushort4* __restrict__ s, int n4) {
    for (int i = blockIdx.x * blockDim.x + threadIdx.x; i < n4; i += gridDim.x * blockDim.x) {
        float4 v = w[i];
        ushort4 o;
        o.x = v.x > 0.f ? 0x3F80u : (v.x < 0.f ? 0xBF80u : 0u);
        o.y = v.y > 0.f ? 0x3F80u : (v.y < 0.f ? 0xBF80u : 0u);
        o.z = v.z > 0.f ? 0x3F80u : (v.z < 0.f ? 0xBF80u : 0u);
        o.w = v.w > 0.f ? 0x3F80u : (v.w < 0.f ? 0xBF80u : 0u);
        s[i] = o;
    }
}

// ---------------- fp32 -> bf16 (RNE) for x
__global__ __launch_bounds__(256) void cvt_kernel(const float4* __restrict__ x,
                                                  ushort4* __restrict__ o, int n4) {
    for (int i = blockIdx.x * blockDim.x + threadIdx.x; i < n4; i += gridDim.x * blockDim.x) {
        float4 v = x[i];
        ushort4 u;
        u.x = f2bf(v.x); u.y = f2bf(v.y); u.z = f2bf(v.z); u.w = f2bf(v.w);
        o[i] = u;
    }
}

// ---------------- m97-structure GEMM: C[m][n] = act(scale * sum_k A[m][k]*B[n][k] + bias[n])
// 128x128 tile, BK=32, 256 thr (4 waves 2x2), 4x4 x mfma_f32_16x16x32_bf16 per wave,
// global_load_lds width=16 staging, 2 barriers per K-step.
// ACT: 0 = relu -> bf16 out ; 1 = sigmoid -> f32 out
template <int ACT>
__global__ __launch_bounds__(256) void gemm_bwn(const ushort_t* __restrict__ A,
                                                const ushort_t* __restrict__ B,
                                                const float* __restrict__ sumptr, float inv_n,
                                                const float* __restrict__ bias,
                                                void* __restrict__ out,
                                                int M, int N, int K) {
    __shared__ __align__(16) ushort_t As[128 * 32];  // [row][k], 64 B rows
    __shared__ __align__(16) ushort_t Bs[128 * 32];

    const int t    = threadIdx.x;
    const int lane = t & 63;
    const int w    = t >> 6;
    const int tm   = blockIdx.y, tn = blockIdx.x;

    // staging: thread t covers 16 B at linear LDS byte t*16 (+4096 for rows 64..127)
    const int   srow  = t >> 2;             // 0..63
    const int   scolb = (t & 3) * 16;       // byte col within 64 B row
    const char* Abase = (const char*)A + ((size_t)(tm * 128 + srow) * K) * 2 + scolb;
    const char* Bbase = (const char*)B + ((size_t)(tn * 128 + srow) * K) * 2 + scolb;
    const size_t rowskip = (size_t)64 * K * 2;  // +64 rows

    AS3 char* lA = (AS3 char*)As;
    AS3 char* lB = (AS3 char*)Bs;
    const int lbase = w * 1024;  // wave-uniform LDS base (HW adds lane*16)

    const int fr = lane & 15;          // fragment row/col within 16
    const int fk = (lane >> 4) * 16;   // byte offset of this lane's 8 K-elems
    const int rm = (w >> 1) * 64;      // wave row base in tile
    const int rn = (w & 1) * 64;       // wave col base in tile

    f32x4 acc[4][4] = {};

    for (int kt = 0; kt < K; kt += 32) {
        __syncthreads();  // previous compute done before overwriting LDS
        const size_t ko = (size_t)kt * 2;
        async16(Abase + ko,           lA + lbase);
        async16(Abase + rowskip + ko, lA + lbase + 4096);
        async16(Bbase + ko,           lB + lbase);
        async16(Bbase + rowskip + ko, lB + lbase + 4096);
        __syncthreads();  // drains vmcnt: tiles resident

        bf16x8 af[4], bf[4];
#pragma unroll
        for (int i = 0; i < 4; ++i)
            af[i] = *(const bf16x8*)((const char*)As + (rm + i * 16 + fr) * 64 + fk);
#pragma unroll
        for (int j = 0; j < 4; ++j)
            bf[j] = *(const bf16x8*)((const char*)Bs + (rn + j * 16 + fr) * 64 + fk);
#pragma unroll
        for (int i = 0; i < 4; ++i)
#pragma unroll
            for (int j = 0; j < 4; ++j)
                acc[i][j] = __builtin_amdgcn_mfma_f32_16x16x32_bf16(af[i], bf[j], acc[i][j], 0, 0, 0);
    }

    // epilogue: C/D layout col=lane&15, row=(lane>>4)*4+reg  [m89/m91 verified]
    const float scale = sumptr[0] * inv_n;
    const int   r0    = (lane >> 4) * 4;
#pragma unroll
    for (int j = 0; j < 4; ++j) {
        const int   col = tn * 128 + rn + j * 16 + fr;
        const float bj  = bias[col];
#pragma unroll
        for (int i = 0; i < 4; ++i) {
            const int rowb = tm * 128 + rm + i * 16 + r0;
#pragma unroll
            for (int r = 0; r < 4; ++r) {
                float v = acc[i][j][r] * scale + bj;
                if (ACT == 0) {
                    v = fmaxf(v, 0.f);
                    ((ushort_t*)out)[(size_t)(rowb + r) * N + col] = f2bf(v);
                } else {
                    v = 1.f / (1.f + __expf(-v));
                    ((float*)out)[(size_t)(rowb + r) * N + col] = v;
                }
            }
        }
    }
}

extern "C" void kernel_launch(void* const* d_in, const int* in_sizes, int n_in,
                              void* d_out, int out_size, void* d_ws, size_t ws_size,
                              hipStream_t stream) {
    const float* x  = (const float*)d_in[0];
    const float* w1 = (const float*)d_in[1];
    const float* b1 = (const float*)d_in[2];
    const float* w2 = (const float*)d_in[3];
    const float* b2 = (const float*)d_in[4];
    const float* w3 = (const float*)d_in[5];
    const float* b3 = (const float*)d_in[6];

    const size_t MB = 1024ull * 1024ull;
    char* ws = (char*)d_ws;
    float*    scales = (float*)ws;
    ushort_t* bufA = (ushort_t*)(ws + 256);             // 64 MB: x_bf16, then h2
    ushort_t* bufB = (ushort_t*)(ws + 256 + 64 * MB);   // 64 MB: h1
    ushort_t* bufC = (ushort_t*)(ws + 256 + 128 * MB);  // 32 MB: s1 -> s2 -> s3

    zero3_kernel<<<1, 64, 0, stream>>>(scales);

    absmean_kernel<<<2048, 256, 0, stream>>>((const float4*)w1, 16777216 / 4, scales + 0);
    absmean_kernel<<<2048, 256, 0, stream>>>((const float4*)w2, 16777216 / 4, scales + 1);
    absmean_kernel<<<1024, 256, 0, stream>>>((const float4*)w3, 4194304 / 4, scales + 2);

    // L1: relu(x @ sign(w1)^T * s1 + b1) -> h1 (bf16)
    sign_kernel<<<2048, 256, 0, stream>>>((const float4*)w1, (ushort4*)bufC, 16777216 / 4);
    cvt_kernel<<<2048, 256, 0, stream>>>((const float4*)x, (ushort4*)bufA, 33554432 / 4);
    gemm_bwn<0><<<dim3(32, 64), 256, 0, stream>>>(bufA, bufC, scales + 0, 1.f / 16777216.f,
                                                  b1, bufB, 8192, 4096, 4096);

    // L2: relu(h1 @ sign(w2)^T * s2 + b2) -> h2 (bf16, overwrites x_bf16)
    sign_kernel<<<2048, 256, 0, stream>>>((const float4*)w2, (ushort4*)bufC, 16777216 / 4);
    gemm_bwn<0><<<dim3(32, 64), 256, 0, stream>>>(bufB, bufC, scales + 1, 1.f / 16777216.f,
                                                  b2, bufA, 8192, 4096, 4096);

    // L3: sigmoid(h2 @ sign(w3)^T * s3 + b3) -> out (f32)
    sign_kernel<<<1024, 256, 0, stream>>>((const float4*)w3, (ushort4*)bufC, 4194304 / 4);
    gemm_bwn<1><<<dim3(8, 64), 256, 0, stream>>>(bufA, bufC, scales + 2, 1.f / 4194304.f,
                                                 b3, d_out, 8192, 1024, 4096);
}

// Round 3
// 934.357 us; speedup vs baseline: 1.2240x; 1.2240x over previous
//
#include <hip/hip_runtime.h>

// Binary-weight MLP: h1=relu(x@sign(w1)^T*s1+b1); h2=relu(h1@...); out=sigmoid(h2@...)
// Weights -> exact bf16 {-1,0,+1}; activations -> bf16; fp32 MFMA accum; scalar
// scale (mean|w|) applied in fp32 epilogue.
//
// GEMM1/2: 256x256 8-phase template (T2 swizzle + T3/T4 counted vmcnt + T5 setprio).
// GEMM3 (N=1024): 128x128 m97-structure kernel (grid too small for 256^2 tiles).
//
// ws layout (160 MB + 256 B), time-multiplexed:
//   scales: 3 floats | bufA 64MB: x_bf16 -> h2 | bufB 64MB: h1 | bufC 32MB: sign(w*)

typedef __bf16 bf16x8 __attribute__((ext_vector_type(8)));
typedef float  f32x4  __attribute__((ext_vector_type(4)));
typedef unsigned short ushort_t;

#define AS1 __attribute__((address_space(1)))
#define AS3 __attribute__((address_space(3)))

__device__ __forceinline__ void async16(const void* g, AS3 void* l) {
    __builtin_amdgcn_global_load_lds((AS1 void*)const_cast<void*>(g), l, 16, 0, 0);
}

__device__ __forceinline__ ushort_t f2bf(float f) {
    unsigned u = __float_as_uint(f);
    u += 0x7FFFu + ((u >> 16) & 1u);   // RNE
    return (ushort_t)(u >> 16);
}

// ---------------- zero the 3 scale accumulators
__global__ void zero3_kernel(float* p) {
    if (threadIdx.x < 3) p[threadIdx.x] = 0.f;
}

// ---------------- fused sign + abs-mean: read w once, write bf16 sign, atomic sum
__global__ __launch_bounds__(256) void binarize_kernel(const float4* __restrict__ w,
                                                       ushort4* __restrict__ s, int n4,
                                                       float* __restrict__ out) {
    float acc = 0.f;
    for (int i = blockIdx.x * blockDim.x + threadIdx.x; i < n4; i += gridDim.x * blockDim.x) {
        float4 v = w[i];
        acc += fabsf(v.x) + fabsf(v.y) + fabsf(v.z) + fabsf(v.w);
        ushort4 o;
        o.x = v.x > 0.f ? 0x3F80u : (v.x < 0.f ? 0xBF80u : 0u);
        o.y = v.y > 0.f ? 0x3F80u : (v.y < 0.f ? 0xBF80u : 0u);
        o.z = v.z > 0.f ? 0x3F80u : (v.z < 0.f ? 0xBF80u : 0u);
        o.w = v.w > 0.f ? 0x3F80u : (v.w < 0.f ? 0xBF80u : 0u);
        s[i] = o;
    }
#pragma unroll
    for (int off = 32; off > 0; off >>= 1) acc += __shfl_down(acc, off);
    __shared__ float wsum[4];
    if ((threadIdx.x & 63) == 0) wsum[threadIdx.x >> 6] = acc;
    __syncthreads();
    if (threadIdx.x == 0) atomicAdd(out, wsum[0] + wsum[1] + wsum[2] + wsum[3]);
}

// ---------------- fp32 -> bf16 (RNE) for x
__global__ __launch_bounds__(256) void cvt_kernel(const float4* __restrict__ x,
                                                  ushort4* __restrict__ o, int n4) {
    for (int i = blockIdx.x * blockDim.x + threadIdx.x; i < n4; i += gridDim.x * blockDim.x) {
        float4 v = x[i];
        ushort4 u;
        u.x = f2bf(v.x); u.y = f2bf(v.y); u.z = f2bf(v.z); u.w = f2bf(v.w);
        o[i] = u;
    }
}

// ================= 256x256 8-phase GEMM (T2+T3+T4+T5) =================
// C[m][n] = act(scale * sum_k A[m][k]*B[n][k] + bias[n]); A:[M][K] B:[N][K] bf16.
// 512 thr = 8 waves (2M x 4N); per-wave C: 128x64 = acc[8][4] f32x4.
// LDS 128 KiB: buf d at d*65536 (A), +32768 (B); tile [256][64] bf16, 128 B rows,
// half h at +h*16384. Swizzle: byte-in-row ^= ((row&7)<<4) on global src + ds_read.
template <int ACT>
__global__ __launch_bounds__(512, 2) void gemm256(const ushort_t* __restrict__ A,
                                                  const ushort_t* __restrict__ B,
                                                  const float* __restrict__ sumptr, float inv_n,
                                                  const float* __restrict__ bias,
                                                  void* __restrict__ out,
                                                  int M, int N, int K) {
    __shared__ __align__(16) char smem[131072];

    const int T    = threadIdx.x;
    const int lane = T & 63;
    const int w    = T >> 6;
    const int wm   = w >> 2, wn = w & 3;
    const int bm   = blockIdx.y * 256;
    const int bn   = blockIdx.x * 256;

    const size_t ldab = (size_t)K * 2;  // row bytes

    // staging source (pre-swizzled global address, rule #21)
    const int srow = T >> 3;                                   // 0..63
    const int cswz = ((T & 7) << 4) ^ ((srow & 7) << 4);       // byte in 128B row-chunk
    const char*  Ag = (const char*)A + (size_t)(bm + srow) * ldab + cswz;
    const char*  Bg = (const char*)B + (size_t)(bn + srow) * ldab + cswz;
    const size_t half_rows = 128 * ldab, l1_rows = 64 * ldab;

    AS3 char* lds  = (AS3 char*)smem;
    const int dstw = w * 1024;  // wave-uniform dest base (HW adds lane*16)

    auto stageA = [&](int s, int h) {
        const char* src = Ag + (size_t)h * half_rows + (size_t)s * 128;
        AS3 char*   d   = lds + (s & 1) * 65536 + h * 16384 + dstw;
        async16(src, d);
        async16(src + l1_rows, d + 8192);
    };
    auto stageB = [&](int s, int h) {
        const char* src = Bg + (size_t)h * half_rows + (size_t)s * 128;
        AS3 char*   d   = lds + (s & 1) * 65536 + 32768 + h * 16384 + dstw;
        async16(src, d);
        async16(src + l1_rows, d + 8192);
    };

    // fragment read bases
    const int axor = (lane & 7) << 4;
    const int arow = wm * 128 + (lane & 15);
    const int brow = wn * 64 + (lane & 15);
    const int kb   = (lane >> 4) * 16;

    f32x4 acc[8][4] = {};
    const int NT = K >> 6;

    // prologue: B0(0) B1(0) A0(0) A1(0) B0(1) B1(1); tile0 resident, 4 loads in flight
    stageB(0, 0); stageB(0, 1); stageA(0, 0); stageA(0, 1);
    stageB(1, 0); stageB(1, 1);
    asm volatile("s_waitcnt vmcnt(4)" ::: "memory");
    __builtin_amdgcn_s_barrier();

    for (int t = 0; t < NT; ++t) {
        const char* As_ = (const char*)smem + (t & 1) * 65536;
        const char* Bs_ = As_ + 32768;

        bf16x8 a0[4][2], a1[4][2], b0[2][2], b1[2][2];

        // ---- phase 0: read A m0-3 (8) + B n0-1 (4); stage A0(t+1); MFMA quad(0,0)
#pragma unroll
        for (int m = 0; m < 4; ++m)
#pragma unroll
            for (int kk = 0; kk < 2; ++kk)
                a0[m][kk] = *(const bf16x8*)(As_ + (arow + m * 16) * 128 + ((kk * 64 + kb) ^ axor));
#pragma unroll
        for (int n = 0; n < 2; ++n)
#pragma unroll
            for (int kk = 0; kk < 2; ++kk)
                b0[n][kk] = *(const bf16x8*)(Bs_ + (brow + n * 16) * 128 + ((kk * 64 + kb) ^ axor));
        if (t + 1 < NT) stageA(t + 1, 0);
        __builtin_amdgcn_s_barrier();
        asm volatile("s_waitcnt lgkmcnt(0)");
        __builtin_amdgcn_s_setprio(1);
#pragma unroll
        for (int m = 0; m < 4; ++m)
#pragma unroll
            for (int n = 0; n < 2; ++n)
#pragma unroll
                for (int kk = 0; kk < 2; ++kk)
                    acc[m][n] = __builtin_amdgcn_mfma_f32_16x16x32_bf16(a0[m][kk], b0[n][kk], acc[m][n], 0, 0, 0);
        __builtin_amdgcn_s_setprio(0);
        __builtin_amdgcn_s_barrier();

        // ---- phase 1: read B n2-3 (4); stage A1(t+1); MFMA quad(0,1)
#pragma unroll
        for (int n = 0; n < 2; ++n)
#pragma unroll
            for (int kk = 0; kk < 2; ++kk)
                b1[n][kk] = *(const bf16x8*)(Bs_ + (brow + 32 + n * 16) * 128 + ((kk * 64 + kb) ^ axor));
        if (t + 1 < NT) stageA(t + 1, 1);
        __builtin_amdgcn_s_barrier();
        asm volatile("s_waitcnt lgkmcnt(0)");
        __builtin_amdgcn_s_setprio(1);
#pragma unroll
        for (int m = 0; m < 4; ++m)
#pragma unroll
            for (int n = 0; n < 2; ++n)
#pragma unroll
                for (int kk = 0; kk < 2; ++kk)
                    acc[m][n + 2] = __builtin_amdgcn_mfma_f32_16x16x32_bf16(a0[m][kk], b1[n][kk], acc[m][n + 2], 0, 0, 0);
        __builtin_amdgcn_s_setprio(0);
        __builtin_amdgcn_s_barrier();

        // ---- phase 2: read A m4-7 (8); stage B0(t+2); MFMA quad(1,0)
#pragma unroll
        for (int m = 0; m < 4; ++m)
#pragma unroll
            for (int kk = 0; kk < 2; ++kk)
                a1[m][kk] = *(const bf16x8*)(As_ + (arow + 64 + m * 16) * 128 + ((kk * 64 + kb) ^ axor));
        if (t + 2 < NT) stageB(t + 2, 0);
        __builtin_amdgcn_s_barrier();
        asm volatile("s_waitcnt lgkmcnt(0)");
        __builtin_amdgcn_s_setprio(1);
#pragma unroll
        for (int m = 0; m < 4; ++m)
#pragma unroll
            for (int n = 0; n < 2; ++n)
#pragma unroll
                for (int kk = 0; kk < 2; ++kk)
                    acc[m + 4][n] = __builtin_amdgcn_mfma_f32_16x16x32_bf16(a1[m][kk], b0[n][kk], acc[m + 4][n], 0, 0, 0);
        __builtin_amdgcn_s_setprio(0);
        __builtin_amdgcn_s_barrier();

        // ---- phase 3: stage B1(t+2); MFMA quad(1,1); counted vmcnt; tile barrier
        if (t + 2 < NT) stageB(t + 2, 1);
        __builtin_amdgcn_s_barrier();
        __builtin_amdgcn_s_setprio(1);
#pragma unroll
        for (int m = 0; m < 4; ++m)
#pragma unroll
            for (int n = 0; n < 2; ++n)
#pragma unroll
                for (int kk = 0; kk < 2; ++kk)
                    acc[m + 4][n + 2] = __builtin_amdgcn_mfma_f32_16x16x32_bf16(a1[m][kk], b1[n][kk], acc[m + 4][n + 2], 0, 0, 0);
        __builtin_amdgcn_s_setprio(0);
        if (t < NT - 2) {
            asm volatile("s_waitcnt vmcnt(4)" ::: "memory");  // keep B(t+2) halves in flight
        } else {
            asm volatile("s_waitcnt vmcnt(0)" ::: "memory");  // drain at the tail only
        }
        __builtin_amdgcn_s_barrier();
    }

    // epilogue: C/D layout col=lane&15, row=(lane>>4)*4+reg  [m89/m91]
    const float scale = sumptr[0] * inv_n;
    const int   r0    = (lane >> 4) * 4;
#pragma unroll
    for (int nj = 0; nj < 4; ++nj) {
        const int   col = bn + wn * 64 + nj * 16 + (lane & 15);
        const float bj  = bias[col];
#pragma unroll
        for (int mi = 0; mi < 8; ++mi) {
            const int rowb = bm + wm * 128 + mi * 16 + r0;
#pragma unroll
            for (int r = 0; r < 4; ++r) {
                float v = acc[mi][nj][r] * scale + bj;
                if (ACT == 0) {
                    v = fmaxf(v, 0.f);
                    ((ushort_t*)out)[(size_t)(rowb + r) * N + col] = f2bf(v);
                } else {
                    v = 1.f / (1.f + __expf(-v));
                    ((float*)out)[(size_t)(rowb + r) * N + col] = v;
                }
            }
        }
    }
}

// ================= 128x128 m97-structure GEMM (layer 3) =================
template <int ACT>
__global__ __launch_bounds__(256) void gemm_bwn(const ushort_t* __restrict__ A,
                                                const ushort_t* __restrict__ B,
                                                const float* __restrict__ sumptr, float inv_n,
                                                const float* __restrict__ bias,
                                                void* __restrict__ out,
                                                int M, int N, int K) {
    __shared__ __align__(16) ushort_t As[128 * 32];
    __shared__ __align__(16) ushort_t Bs[128 * 32];

    const int t    = threadIdx.x;
    const int lane = t & 63;
    const int w    = t >> 6;
    const int tm   = blockIdx.y, tn = blockIdx.x;

    const int   srow  = t >> 2;
    const int   scolb = (t & 3) * 16;
    const char* Abase = (const char*)A + ((size_t)(tm * 128 + srow) * K) * 2 + scolb;
    const char* Bbase = (const char*)B + ((size_t)(tn * 128 + srow) * K) * 2 + scolb;
    const size_t rowskip = (size_t)64 * K * 2;

    AS3 char* lA = (AS3 char*)As;
    AS3 char* lB = (AS3 char*)Bs;
    const int lbase = w * 1024;

    const int fr = lane & 15;
    const int fk = (lane >> 4) * 16;
    const int rm = (w >> 1) * 64;
    const int rn = (w & 1) * 64;

    f32x4 acc[4][4] = {};

    for (int kt = 0; kt < K; kt += 32) {
        __syncthreads();
        const size_t ko = (size_t)kt * 2;
        async16(Abase + ko,           lA + lbase);
        async16(Abase + rowskip + ko, lA + lbase + 4096);
        async16(Bbase + ko,           lB + lbase);
        async16(Bbase + rowskip + ko, lB + lbase + 4096);
        __syncthreads();

        bf16x8 af[4], bf[4];
#pragma unroll
        for (int i = 0; i < 4; ++i)
            af[i] = *(const bf16x8*)((const char*)As + (rm + i * 16 + fr) * 64 + fk);
#pragma unroll
        for (int j = 0; j < 4; ++j)
            bf[j] = *(const bf16x8*)((const char*)Bs + (rn + j * 16 + fr) * 64 + fk);
#pragma unroll
        for (int i = 0; i < 4; ++i)
#pragma unroll
            for (int j = 0; j < 4; ++j)
                acc[i][j] = __builtin_amdgcn_mfma_f32_16x16x32_bf16(af[i], bf[j], acc[i][j], 0, 0, 0);
    }

    const float scale = sumptr[0] * inv_n;
    const int   r0    = (lane >> 4) * 4;
#pragma unroll
    for (int j = 0; j < 4; ++j) {
        const int   col = tn * 128 + rn + j * 16 + fr;
        const float bj  = bias[col];
#pragma unroll
        for (int i = 0; i < 4; ++i) {
            const int rowb = tm * 128 + rm + i * 16 + r0;
#pragma unroll
            for (int r = 0; r < 4; ++r) {
                float v = acc[i][j][r] * scale + bj;
                if (ACT == 0) {
                    v = fmaxf(v, 0.f);
                    ((ushort_t*)out)[(size_t)(rowb + r) * N + col] = f2bf(v);
                } else {
                    v = 1.f / (1.f + __expf(-v));
                    ((float*)out)[(size_t)(rowb + r) * N + col] = v;
                }
            }
        }
    }
}

extern "C" void kernel_launch(void* const* d_in, const int* in_sizes, int n_in,
                              void* d_out, int out_size, void* d_ws, size_t ws_size,
                              hipStream_t stream) {
    const float* x  = (const float*)d_in[0];
    const float* w1 = (const float*)d_in[1];
    const float* b1 = (const float*)d_in[2];
    const float* w2 = (const float*)d_in[3];
    const float* b2 = (const float*)d_in[4];
    const float* w3 = (const float*)d_in[5];
    const float* b3 = (const float*)d_in[6];

    const size_t MB = 1024ull * 1024ull;
    char* ws = (char*)d_ws;
    float*    scales = (float*)ws;
    ushort_t* bufA = (ushort_t*)(ws + 256);             // 64 MB: x_bf16, then h2
    ushort_t* bufB = (ushort_t*)(ws + 256 + 64 * MB);   // 64 MB: h1
    ushort_t* bufC = (ushort_t*)(ws + 256 + 128 * MB);  // 32 MB: s1 -> s2 -> s3

    zero3_kernel<<<1, 64, 0, stream>>>(scales);

    // L1: relu(x @ sign(w1)^T * s1 + b1) -> h1
    binarize_kernel<<<2048, 256, 0, stream>>>((const float4*)w1, (ushort4*)bufC,
                                              16777216 / 4, scales + 0);
    cvt_kernel<<<2048, 256, 0, stream>>>((const float4*)x, (ushort4*)bufA, 33554432 / 4);
    gemm256<0><<<dim3(16, 32), 512, 0, stream>>>(bufA, bufC, scales + 0, 1.f / 16777216.f,
                                                 b1, bufB, 8192, 4096, 4096);

    // L2: relu(h1 @ sign(w2)^T * s2 + b2) -> h2
    binarize_kernel<<<2048, 256, 0, stream>>>((const float4*)w2, (ushort4*)bufC,
                                              16777216 / 4, scales + 1);
    gemm256<0><<<dim3(16, 32), 512, 0, stream>>>(bufB, bufC, scales + 1, 1.f / 16777216.f,
                                                 b2, bufA, 8192, 4096, 4096);

    // L3: sigmoid(h2 @ sign(w3)^T * s3 + b3) -> out (f32)
    binarize_kernel<<<1024, 256, 0, stream>>>((const float4*)w3, (ushort4*)bufC,
                                              4194304 / 4, scales + 2);
    gemm_bwn<1><<<dim3(8, 64), 256, 0, stream>>>(bufA, bufC, scales + 2, 1.f / 4194304.f,
                                                 b3, d_out, 8192, 1024, 4096);
}